// Round 9
// baseline (590.952 us; speedup 1.0000x reference)
//
#include <hip/hip_runtime.h>
#include <hip/hip_cooperative_groups.h>

namespace cg = cooperative_groups;

#define N_NODES  100000
#define N_EDGES  3200000
#define N_GRAPHS 512
#define F_IN     5
#define F_HID    16

#define PBLK   512                      // sort block size
#define CHUNK  4096                     // edges per sort block
#define NBLK   ((N_EDGES + CHUNK - 1) / CHUNK)          // 782
#define BKT_NODES 256                   // nodes per bucket
#define NBKT ((N_NODES + BKT_NODES - 1) / BKT_NODES)    // 391
#define HPAD   512                      // H row stride
#define CAP    10240                    // per-bucket capacity (mean 8184, +23 sigma)
#define CPT    (CAP / 512)              // csr entries per thread (20)
#define PN     64                       // nodes per pull block (fallback kernels)
#define NPB    ((N_NODES + PN - 1) / PN)                // 1563
#define GRID_F 512                      // fused grid: 2 blocks/CU x 256 CU
#define PNF    128                      // nodes per fused pull iteration (512 thr / 4)
#define NPGF   ((N_NODES + PNF - 1) / PNF)              // 782

// ---------------- helpers ----------------

__device__ inline unsigned short f2bf(float f) {
    unsigned u = __float_as_uint(f);
    return (unsigned short)((u + 0x7fffu + ((u >> 16) & 1u)) >> 16);   // RNE
}
__device__ inline float bf2f(unsigned short h) {
    return __uint_as_float(((unsigned)h) << 16);
}
// unpack one 32 B bf16 row (2 x uint4) into 16 floats (static indexing)
__device__ inline void unpack16(uint4 r0, uint4 r1, float* f) {
    f[0]  = bf2f((unsigned short)r0.x); f[1]  = bf2f((unsigned short)(r0.x >> 16));
    f[2]  = bf2f((unsigned short)r0.y); f[3]  = bf2f((unsigned short)(r0.y >> 16));
    f[4]  = bf2f((unsigned short)r0.z); f[5]  = bf2f((unsigned short)(r0.z >> 16));
    f[6]  = bf2f((unsigned short)r0.w); f[7]  = bf2f((unsigned short)(r0.w >> 16));
    f[8]  = bf2f((unsigned short)r1.x); f[9]  = bf2f((unsigned short)(r1.x >> 16));
    f[10] = bf2f((unsigned short)r1.y); f[11] = bf2f((unsigned short)(r1.y >> 16));
    f[12] = bf2f((unsigned short)r1.z); f[13] = bf2f((unsigned short)(r1.z >> 16));
    f[14] = bf2f((unsigned short)r1.w); f[15] = bf2f((unsigned short)(r1.w >> 16));
}

// block-wide inclusive scan via wave shfl; NW = number of waves (<=8)
template <int NW>
__device__ inline int block_incl_scan(int v, int t, int* wsum) {
    int lane = t & 63, wave = t >> 6;
    int x = v;
#pragma unroll
    for (int o = 1; o < 64; o <<= 1) {
        int y = __shfl_up(x, o, 64);
        if (lane >= o) x += y;
    }
    if (lane == 63) wsum[wave] = x;
    __syncthreads();
    if (t < 64) {
        int w = (t < NW) ? wsum[t] : 0;
#pragma unroll
        for (int o = 1; o < NW; o <<= 1) {
            int y = __shfl_up(w, o, 64);
            if (t >= o) w += y;
        }
        if (t < NW) wsum[t] = w;
    }
    __syncthreads();
    return x + (wave ? wsum[wave - 1] : 0);
}

// ---------------- fused cooperative kernel ----------------

union SMF {
    struct { int hist[HPAD]; } cnt;
    struct { int scn[HPAD]; int base[HPAD];
             unsigned pkd[CHUNK]; unsigned short bkt[CHUNK]; } sc;   // 28.7 KB
    struct { int hist[BKT_NODES]; int beg[BKT_NODES];
             float w1[F_IN * F_HID]; unsigned pkd[CAP]; } csr;       // 43.3 KB
    struct { float w2[F_HID * F_HID]; float b1s[F_HID]; } p1;
    struct { float b2s[F_HID]; float hbuf[PNF][F_HID + 1]; int bl[PNF]; } p2;
};

__global__ __launch_bounds__(512, 2) void k_fused(
        const float* __restrict__ x, const int* __restrict__ ei,
        const int* __restrict__ batch, const float* __restrict__ W1,
        const float* __restrict__ b1, const float* __restrict__ W2,
        const float* __restrict__ b2, float* __restrict__ out,
        int* __restrict__ H, int* __restrict__ Hc, int* __restrict__ cnt_b,
        unsigned short* __restrict__ rnk_e, unsigned* __restrict__ packed,
        int2* __restrict__ rowbc, int* __restrict__ col,
        float* __restrict__ dinv, unsigned short* __restrict__ pb_a,
        unsigned short* __restrict__ pb_b, float* __restrict__ cnt) {
    cg::grid_group grid = cg::this_grid();
    const int* src = ei;
    const int* dst = ei + N_EDGES;
    int t = threadIdx.x, bid = blockIdx.x;
    static __shared__ SMF sm;
    __shared__ int wsum[8];
    __shared__ int bcnt[8];
    __shared__ int g0s, tots;

    // ---- P0: zero out/cnt ----
    {
        int i = bid * 512 + t;
        if (i < N_GRAPHS * F_HID) out[i] = 0.0f;
        if (i < N_GRAPHS) cnt[i] = 0.0f;
    }
    grid.sync();

    // ---- P1: count (hist of dst>>8; rank stored to rnk_e) ----
    for (int blk = bid; blk < NBLK; blk += GRID_F) {
        int chunk0 = blk * CHUNK;
        int n4 = min(CHUNK, N_EDGES - chunk0) >> 2;
        sm.cnt.hist[t] = 0;
        __syncthreads();
        const int4* d4 = (const int4*)(dst + chunk0);
        ushort4* r4 = (ushort4*)(rnk_e + chunk0);
#pragma unroll
        for (int i = 0; i < CHUNK / 4 / PBLK; i++) {
            int k = t + i * PBLK;
            if (k < n4) {
                int4 d = d4[k];
                ushort4 rr;
                rr.x = (unsigned short)atomicAdd(&sm.cnt.hist[d.x >> 8], 1);
                rr.y = (unsigned short)atomicAdd(&sm.cnt.hist[d.y >> 8], 1);
                rr.z = (unsigned short)atomicAdd(&sm.cnt.hist[d.z >> 8], 1);
                rr.w = (unsigned short)atomicAdd(&sm.cnt.hist[d.w >> 8], 1);
                r4[k] = rr;
            }
        }
        __syncthreads();
        int v = sm.cnt.hist[t];
        H[blk * HPAD + t] = v;
        Hc[blk * HPAD + t] = v;
        __syncthreads();                            // guard hist reuse
    }
    grid.sync();

    // ---- P2: scan (H in place; bucket totals) ----
    for (int b = bid; b < NBKT; b += GRID_F) {
        int v[2];
        int s = 0;
#pragma unroll
        for (int i = 0; i < 2; i++) {
            int pos = t * 2 + i;
            v[i] = (pos < NBLK) ? H[pos * HPAD + b] : 0;
            s += v[i];
        }
        int incl = block_incl_scan<8>(s, t, wsum);
        int run = incl - s;
#pragma unroll
        for (int i = 0; i < 2; i++) {
            int pos = t * 2 + i;
            if (pos < NBLK) H[pos * HPAD + b] = run;
            run += v[i];
        }
        if (t == 511) cnt_b[b] = incl;
        __syncthreads();                            // guard wsum reuse
    }
    grid.sync();

    // ---- P3: zero-atomic scatter (positions fully precomputed) ----
    for (int blk = bid; blk < NBLK; blk += GRID_F) {
        int chunk0 = blk * CHUNK;
        int n = min(CHUNK, N_EDGES - chunk0);
        int n4 = n >> 2;
        sm.sc.base[t] = H[blk * HPAD + t];
        int v = Hc[blk * HPAD + t];
        int incl = block_incl_scan<8>(v, t, wsum);
        sm.sc.scn[t] = incl - v;
        __syncthreads();
        const int4* s4 = (const int4*)(src + chunk0);
        const int4* d4 = (const int4*)(dst + chunk0);
        const ushort4* r4 = (const ushort4*)(rnk_e + chunk0);
#pragma unroll
        for (int i = 0; i < CHUNK / 4 / PBLK; i++) {
            int k = t + i * PBLK;
            if (k < n4) {
                int4 s = s4[k], d = d4[k];
                ushort4 r = r4[k];
                int b0 = d.x >> 8, b1_ = d.y >> 8, b2_ = d.z >> 8, b3 = d.w >> 8;
                int p0 = sm.sc.scn[b0] + r.x;
                sm.sc.pkd[p0] = ((unsigned)s.x << 8) | (unsigned)(d.x & 255);
                sm.sc.bkt[p0] = (unsigned short)b0;
                int p1 = sm.sc.scn[b1_] + r.y;
                sm.sc.pkd[p1] = ((unsigned)s.y << 8) | (unsigned)(d.y & 255);
                sm.sc.bkt[p1] = (unsigned short)b1_;
                int p2 = sm.sc.scn[b2_] + r.z;
                sm.sc.pkd[p2] = ((unsigned)s.z << 8) | (unsigned)(d.z & 255);
                sm.sc.bkt[p2] = (unsigned short)b2_;
                int p3 = sm.sc.scn[b3] + r.w;
                sm.sc.pkd[p3] = ((unsigned)s.w << 8) | (unsigned)(d.w & 255);
                sm.sc.bkt[p3] = (unsigned short)b3;
            }
        }
        __syncthreads();
        for (int p = t; p < n; p += PBLK) {         // coalesced flush
            int b = sm.sc.bkt[p];
            packed[(size_t)b * CAP + sm.sc.base[b] + (p - sm.sc.scn[b])] = sm.sc.pkd[p];
        }
        __syncthreads();                            // guard pkd/bkt reuse
    }
    grid.sync();

    // ---- P4: csr (node sort, 1 atomic/edge) + dinv + x@W1 + graph counts ----
    for (int b = bid; b < NBKT; b += GRID_F) {
        int gbase = b * CAP;
        if (t < BKT_NODES) sm.csr.hist[t] = 0;
        if (t < 8) bcnt[t] = 0;
        if (t == 0) {
            tots = min(cnt_b[b], CAP);
            g0s = batch[b * BKT_NODES];
        }
        if (t >= 512 - F_IN * F_HID)
            sm.csr.w1[t - (512 - F_IN * F_HID)] = W1[t - (512 - F_IN * F_HID)];
        __syncthreads();
        int tot = tots;
        const unsigned* pk = packed + (size_t)b * CAP;
        int r2[CPT];
#pragma unroll
        for (int i = 0; i < CPT; i++) {
            int k = t + i * 512;
            if (k < tot) {
                unsigned u = pk[k];
                sm.csr.pkd[k] = u;
                r2[i] = atomicAdd(&sm.csr.hist[u & 255], 1);
            }
        }
        __syncthreads();
        int v = (t < BKT_NODES) ? sm.csr.hist[t] : 0;
        int incl = block_incl_scan<8>(v, t, wsum);
        if (t < BKT_NODES) sm.csr.beg[t] = incl - v;
        __syncthreads();
#pragma unroll
        for (int i = 0; i < CPT; i++) {             // no second atomic
            int k = t + i * 512;
            if (k < tot) {
                unsigned w = sm.csr.pkd[k];
                col[gbase + sm.csr.beg[w & 255] + r2[i]] = (int)(w >> 8);
            }
        }
        if (t < BKT_NODES) {
            int node = b * BKT_NODES + t;
            if (node < N_NODES) {
                rowbc[node] = make_int2(gbase + sm.csr.beg[t], v);
                float di = rsqrtf((float)(1 + v));  // +1 self loop
                dinv[node] = di;
                int g = batch[node];                // graph-size counting
                int l = g - g0s;
                if (l >= 0 && l < 8) atomicAdd(&bcnt[l], 1);
                else atomicAdd(&cnt[g], 1.0f);
                float xi[F_IN];
#pragma unroll
                for (int k = 0; k < F_IN; k++) xi[k] = x[node * F_IN + k];
                unsigned pkk[8];
#pragma unroll
                for (int q = 0; q < 8; q++) {
                    float h0 = 0.0f, h1 = 0.0f;
#pragma unroll
                    for (int k = 0; k < F_IN; k++) {
                        h0 += xi[k] * sm.csr.w1[k * F_HID + 2 * q];
                        h1 += xi[k] * sm.csr.w1[k * F_HID + 2 * q + 1];
                    }
                    pkk[q] = (unsigned)f2bf(h0 * di) | ((unsigned)f2bf(h1 * di) << 16);
                }
                uint4* d4 = (uint4*)(pb_a + (size_t)node * F_HID);
                d4[0] = make_uint4(pkk[0], pkk[1], pkk[2], pkk[3]);
                d4[1] = make_uint4(pkk[4], pkk[5], pkk[6], pkk[7]);
            }
        }
        __syncthreads();
        if (t < 8 && bcnt[t] > 0) atomicAdd(&cnt[g0s + t], (float)bcnt[t]);
        __syncthreads();                            // guard bcnt/g0s/pkd reuse
    }
    grid.sync();

    // ---- P5: pull1 (gather + relu + @W2) ----
    if (t < F_HID * F_HID) sm.p1.w2[t] = W2[t];
    if (t >= 256 && t < 256 + F_HID) sm.p1.b1s[t - 256] = b1[t - 256];
    __syncthreads();
    for (int gw = bid; gw < NPGF; gw += GRID_F) {
        int nl = t >> 2, q = t & 3;
        int node = gw * PNF + nl;
        const uint4* pb16 = (const uint4*)pb_a;
        float f[F_HID];
#pragma unroll
        for (int c = 0; c < F_HID; c++) f[c] = 0.0f;
        if (node < N_NODES) {
            int2 rc = rowbc[node];
            if (q == 0) unpack16(pb16[2 * node], pb16[2 * node + 1], f);
            for (int i = q; i < rc.y; i += 4) {
                int s = col[rc.x + i];
                uint4 r0 = pb16[2 * s], r1 = pb16[2 * s + 1];
                float g[F_HID];
                unpack16(r0, r1, g);
#pragma unroll
                for (int c = 0; c < F_HID; c++) f[c] += g[c];
            }
        }
#pragma unroll
        for (int c = 0; c < F_HID; c++) {           // quad reduce
            f[c] += __shfl_xor(f[c], 1, 64);
            f[c] += __shfl_xor(f[c], 2, 64);
        }
        if (node < N_NODES) {
            float di = dinv[node];
            float h[F_HID];
#pragma unroll
            for (int c = 0; c < F_HID; c++)
                h[c] = fmaxf(di * f[c] + sm.p1.b1s[c], 0.0f);
            float m0 = 0.0f, m1 = 0.0f, m2 = 0.0f, m3 = 0.0f;
#pragma unroll
            for (int c = 0; c < F_HID; c++) {
                float4 wv = *(const float4*)&sm.p1.w2[c * F_HID + 4 * q];
                m0 += h[c] * wv.x; m1 += h[c] * wv.y;
                m2 += h[c] * wv.z; m3 += h[c] * wv.w;
            }
            unsigned p0 = (unsigned)f2bf(m0 * di) | ((unsigned)f2bf(m1 * di) << 16);
            unsigned p1 = (unsigned)f2bf(m2 * di) | ((unsigned)f2bf(m3 * di) << 16);
            *(uint2*)(pb_b + (size_t)node * F_HID + 4 * q) = make_uint2(p0, p1);
        }
    }
    grid.sync();

    // ---- P6: pull2 + fused mean-pool ----
    for (int gw = bid; gw < NPGF; gw += GRID_F) {
        if (t < F_HID) sm.p2.b2s[t] = b2[t];
        if (t < PNF) {
            int nn = gw * PNF + t;
            sm.p2.bl[t] = (nn < N_NODES) ? batch[nn] : -1;
        }
        __syncthreads();
        int nl = t >> 2, q = t & 3;
        int node = gw * PNF + nl;
        const uint4* pb16 = (const uint4*)pb_b;
        float f[F_HID];
#pragma unroll
        for (int c = 0; c < F_HID; c++) f[c] = 0.0f;
        if (node < N_NODES) {
            int2 rc = rowbc[node];
            if (q == 0) unpack16(pb16[2 * node], pb16[2 * node + 1], f);
            for (int i = q; i < rc.y; i += 4) {
                int s = col[rc.x + i];
                uint4 r0 = pb16[2 * s], r1 = pb16[2 * s + 1];
                float g[F_HID];
                unpack16(r0, r1, g);
#pragma unroll
                for (int c = 0; c < F_HID; c++) f[c] += g[c];
            }
        }
#pragma unroll
        for (int c = 0; c < F_HID; c++) {
            f[c] += __shfl_xor(f[c], 1, 64);
            f[c] += __shfl_xor(f[c], 2, 64);
        }
        if (node < N_NODES && q == 0) {
            float di = dinv[node];
#pragma unroll
            for (int c = 0; c < F_HID; c++)
                sm.p2.hbuf[nl][c] = fmaxf(di * f[c] + sm.p2.b2s[c], 0.0f);
        }
        __syncthreads();
        if (t < 8 * F_HID) {                        // (local graph l, channel ch)
            int l = t >> 4, ch = t & 15;
            int g = sm.p2.bl[0] + l;
            if (g < N_GRAPHS) {
                float s = 0.0f;
                int m = 0;
                for (int n0 = 0; n0 < PNF; n0++) {
                    int n = (n0 + (ch << 3)) & (PNF - 1);   // stagger
                    if (sm.p2.bl[n] == g) { s += sm.p2.hbuf[n][ch]; m++; }
                }
                if (m > 0) atomicAdd(&out[g * F_HID + ch], s / cnt[g]);
            }
        }
        __syncthreads();                            // guard bl/hbuf reuse
    }
}

// ---------------- fallback kernels (r8-verified 7-kernel path) ----------------

__global__ __launch_bounds__(256) void k_zero(float* __restrict__ out,
                                              float* __restrict__ cnt) {
    int i = blockIdx.x * 256 + threadIdx.x;
    if (i < N_GRAPHS * F_HID) out[i] = 0.0f;
    if (i < N_GRAPHS) cnt[i] = 0.0f;
}

__global__ __launch_bounds__(PBLK) void k_count(const int* __restrict__ dst,
                                                const int* __restrict__ batch,
                                                int* __restrict__ H,
                                                int* __restrict__ Hc,
                                                unsigned short* __restrict__ rnk_e,
                                                float* __restrict__ cnt) {
    __shared__ int hist[HPAD];
    __shared__ int bcnt[8];
    __shared__ int g0s;
    int t = threadIdx.x, blk = blockIdx.x;
    int chunk0 = blk * CHUNK;
    int n4 = min(CHUNK, N_EDGES - chunk0) >> 2;
    hist[t] = 0;
    if (t < 8) bcnt[t] = 0;
    if (t == 0 && blk < NBKT) g0s = batch[blk * BKT_NODES];
    __syncthreads();
    const int4* d4 = (const int4*)(dst + chunk0);
    ushort4* r4 = (ushort4*)(rnk_e + chunk0);
#pragma unroll
    for (int i = 0; i < CHUNK / 4 / PBLK; i++) {
        int k = t + i * PBLK;
        if (k < n4) {
            int4 d = d4[k];
            ushort4 rr;
            rr.x = (unsigned short)atomicAdd(&hist[d.x >> 8], 1);
            rr.y = (unsigned short)atomicAdd(&hist[d.y >> 8], 1);
            rr.z = (unsigned short)atomicAdd(&hist[d.z >> 8], 1);
            rr.w = (unsigned short)atomicAdd(&hist[d.w >> 8], 1);
            r4[k] = rr;
        }
    }
    if (blk < NBKT && t < BKT_NODES) {
        int i2 = blk * BKT_NODES + t;
        if (i2 < N_NODES) {
            int g = batch[i2];
            int l = g - g0s;
            if (l >= 0 && l < 8) atomicAdd(&bcnt[l], 1);
            else atomicAdd(&cnt[g], 1.0f);
        }
    }
    __syncthreads();
    int v = hist[t];
    H[blk * HPAD + t] = v;
    Hc[blk * HPAD + t] = v;
    if (blk < NBKT && t < 8 && bcnt[t] > 0) atomicAdd(&cnt[g0s + t], (float)bcnt[t]);
}

__global__ __launch_bounds__(256) void k_scan(int* __restrict__ H,
                                              int* __restrict__ cnt_b) {
    __shared__ int wsum[8];
    int b = blockIdx.x, t = threadIdx.x;
    int v[4];
    int s = 0;
#pragma unroll
    for (int i = 0; i < 4; i++) {
        int pos = t * 4 + i;
        v[i] = (pos < NBLK) ? H[pos * HPAD + b] : 0;
        s += v[i];
    }
    int incl = block_incl_scan<4>(s, t, wsum);
    int run = incl - s;
#pragma unroll
    for (int i = 0; i < 4; i++) {
        int pos = t * 4 + i;
        if (pos < NBLK) H[pos * HPAD + b] = run;
        run += v[i];
    }
    if (t == 255) cnt_b[b] = incl;
}

__global__ __launch_bounds__(PBLK) void k_scatter(const int* __restrict__ src,
                                                  const int* __restrict__ dst,
                                                  const int* __restrict__ H,
                                                  const int* __restrict__ Hc,
                                                  const unsigned short* __restrict__ rnk_e,
                                                  unsigned* __restrict__ packed) {
    __shared__ int scn[HPAD];
    __shared__ int base[HPAD];
    __shared__ int wsum[8];
    __shared__ unsigned pkd[CHUNK];
    __shared__ unsigned short bkt[CHUNK];
    int t = threadIdx.x, blk = blockIdx.x;
    int chunk0 = blk * CHUNK;
    int n = min(CHUNK, N_EDGES - chunk0);
    int n4 = n >> 2;
    base[t] = H[blk * HPAD + t];
    int v = Hc[blk * HPAD + t];
    int incl = block_incl_scan<8>(v, t, wsum);
    scn[t] = incl - v;
    __syncthreads();
    const int4* s4 = (const int4*)(src + chunk0);
    const int4* d4 = (const int4*)(dst + chunk0);
    const ushort4* r4 = (const ushort4*)(rnk_e + chunk0);
#pragma unroll
    for (int i = 0; i < CHUNK / 4 / PBLK; i++) {
        int k = t + i * PBLK;
        if (k < n4) {
            int4 s = s4[k], d = d4[k];
            ushort4 r = r4[k];
            int b0 = d.x >> 8, b1 = d.y >> 8, b2 = d.z >> 8, b3 = d.w >> 8;
            int p0 = scn[b0] + r.x;
            pkd[p0] = ((unsigned)s.x << 8) | (unsigned)(d.x & 255);
            bkt[p0] = (unsigned short)b0;
            int p1 = scn[b1] + r.y;
            pkd[p1] = ((unsigned)s.y << 8) | (unsigned)(d.y & 255);
            bkt[p1] = (unsigned short)b1;
            int p2 = scn[b2] + r.z;
            pkd[p2] = ((unsigned)s.z << 8) | (unsigned)(d.z & 255);
            bkt[p2] = (unsigned short)b2;
            int p3 = scn[b3] + r.w;
            pkd[p3] = ((unsigned)s.w << 8) | (unsigned)(d.w & 255);
            bkt[p3] = (unsigned short)b3;
        }
    }
    __syncthreads();
    for (int p = t; p < n; p += PBLK) {
        int b = bkt[p];
        packed[(size_t)b * CAP + base[b] + (p - scn[b])] = pkd[p];
    }
}

__global__ __launch_bounds__(512) void k_csr(const int* __restrict__ cnt_b,
                                             const unsigned* __restrict__ packed,
                                             const float* __restrict__ x,
                                             const float* __restrict__ W1,
                                             int2* __restrict__ rowbc,
                                             int* __restrict__ col,
                                             float* __restrict__ dinv,
                                             unsigned short* __restrict__ pb) {
    __shared__ int hist[BKT_NODES];
    __shared__ int beg[BKT_NODES];
    __shared__ int wsum[8];
    __shared__ float w1[F_IN * F_HID];
    __shared__ unsigned pkd[CAP];
    __shared__ int tots;
    int b = blockIdx.x, t = threadIdx.x;
    int gbase = b * CAP;
    if (t < BKT_NODES) hist[t] = 0;
    if (t == 0) tots = min(cnt_b[b], CAP);
    if (t >= 512 - F_IN * F_HID) w1[t - (512 - F_IN * F_HID)] = W1[t - (512 - F_IN * F_HID)];
    __syncthreads();
    int tot = tots;
    const unsigned* pk = packed + (size_t)b * CAP;
    int r2[CPT];
#pragma unroll
    for (int i = 0; i < CPT; i++) {
        int k = t + i * 512;
        if (k < tot) {
            unsigned u = pk[k];
            pkd[k] = u;
            r2[i] = atomicAdd(&hist[u & 255], 1);
        }
    }
    __syncthreads();
    int v = (t < BKT_NODES) ? hist[t] : 0;
    int incl = block_incl_scan<8>(v, t, wsum);
    if (t < BKT_NODES) beg[t] = incl - v;
    __syncthreads();
#pragma unroll
    for (int i = 0; i < CPT; i++) {
        int k = t + i * 512;
        if (k < tot) {
            unsigned w = pkd[k];
            col[gbase + beg[w & 255] + r2[i]] = (int)(w >> 8);
        }
    }
    if (t < BKT_NODES) {
        int node = b * BKT_NODES + t;
        if (node < N_NODES) {
            rowbc[node] = make_int2(gbase + beg[t], v);
            float di = rsqrtf((float)(1 + v));
            dinv[node] = di;
            float xi[F_IN];
#pragma unroll
            for (int k = 0; k < F_IN; k++) xi[k] = x[node * F_IN + k];
            unsigned pkk[8];
#pragma unroll
            for (int q = 0; q < 8; q++) {
                float h0 = 0.0f, h1 = 0.0f;
#pragma unroll
                for (int k = 0; k < F_IN; k++) {
                    h0 += xi[k] * w1[k * F_HID + 2 * q];
                    h1 += xi[k] * w1[k * F_HID + 2 * q + 1];
                }
                pkk[q] = (unsigned)f2bf(h0 * di) | ((unsigned)f2bf(h1 * di) << 16);
            }
            uint4* d4 = (uint4*)(pb + (size_t)node * F_HID);
            d4[0] = make_uint4(pkk[0], pkk[1], pkk[2], pkk[3]);
            d4[1] = make_uint4(pkk[4], pkk[5], pkk[6], pkk[7]);
        }
    }
}

__global__ __launch_bounds__(256) void k_pull1(const int2* __restrict__ rowbc,
                                               const int* __restrict__ col,
                                               const unsigned short* __restrict__ pb,
                                               const float* __restrict__ dinv,
                                               const float* __restrict__ W2,
                                               const float* __restrict__ b1,
                                               unsigned short* __restrict__ pb2) {
    __shared__ float w2[F_HID * F_HID];
    __shared__ float b1s[F_HID];
    int t = threadIdx.x;
    w2[t] = W2[t];
    if (t < F_HID) b1s[t] = b1[t];
    __syncthreads();
    int nl = t >> 2, q = t & 3;
    int node = blockIdx.x * PN + nl;
    const uint4* pb16 = (const uint4*)pb;
    float f[F_HID];
#pragma unroll
    for (int c = 0; c < F_HID; c++) f[c] = 0.0f;
    if (node < N_NODES) {
        int2 rc = rowbc[node];
        if (q == 0) unpack16(pb16[2 * node], pb16[2 * node + 1], f);
        for (int i = q; i < rc.y; i += 4) {
            int s = col[rc.x + i];
            uint4 r0 = pb16[2 * s], r1 = pb16[2 * s + 1];
            float g[F_HID];
            unpack16(r0, r1, g);
#pragma unroll
            for (int c = 0; c < F_HID; c++) f[c] += g[c];
        }
    }
#pragma unroll
    for (int c = 0; c < F_HID; c++) {
        f[c] += __shfl_xor(f[c], 1, 64);
        f[c] += __shfl_xor(f[c], 2, 64);
    }
    if (node < N_NODES) {
        float di = dinv[node];
        float h[F_HID];
#pragma unroll
        for (int c = 0; c < F_HID; c++)
            h[c] = fmaxf(di * f[c] + b1s[c], 0.0f);
        float m0 = 0.0f, m1 = 0.0f, m2 = 0.0f, m3 = 0.0f;
#pragma unroll
        for (int c = 0; c < F_HID; c++) {
            float4 wv = *(const float4*)&w2[c * F_HID + 4 * q];
            m0 += h[c] * wv.x; m1 += h[c] * wv.y; m2 += h[c] * wv.z; m3 += h[c] * wv.w;
        }
        unsigned p0 = (unsigned)f2bf(m0 * di) | ((unsigned)f2bf(m1 * di) << 16);
        unsigned p1 = (unsigned)f2bf(m2 * di) | ((unsigned)f2bf(m3 * di) << 16);
        *(uint2*)(pb2 + (size_t)node * F_HID + 4 * q) = make_uint2(p0, p1);
    }
}

__global__ __launch_bounds__(256) void k_pull2(const int2* __restrict__ rowbc,
                                               const int* __restrict__ col,
                                               const unsigned short* __restrict__ pb,
                                               const float* __restrict__ dinv,
                                               const int* __restrict__ batch,
                                               const float* __restrict__ b2,
                                               const float* __restrict__ cnt,
                                               float* __restrict__ out) {
    __shared__ float b2s[F_HID];
    __shared__ float hbuf[PN][F_HID + 1];
    __shared__ int bl[PN];
    int t = threadIdx.x;
    if (t < F_HID) b2s[t] = b2[t];
    if (t < PN) {
        int nn = blockIdx.x * PN + t;
        bl[t] = (nn < N_NODES) ? batch[nn] : -1;
    }
    __syncthreads();
    int nl = t >> 2, q = t & 3;
    int node = blockIdx.x * PN + nl;
    const uint4* pb16 = (const uint4*)pb;
    float f[F_HID];
#pragma unroll
    for (int c = 0; c < F_HID; c++) f[c] = 0.0f;
    if (node < N_NODES) {
        int2 rc = rowbc[node];
        if (q == 0) unpack16(pb16[2 * node], pb16[2 * node + 1], f);
        for (int i = q; i < rc.y; i += 4) {
            int s = col[rc.x + i];
            uint4 r0 = pb16[2 * s], r1 = pb16[2 * s + 1];
            float g[F_HID];
            unpack16(r0, r1, g);
#pragma unroll
            for (int c = 0; c < F_HID; c++) f[c] += g[c];
        }
    }
#pragma unroll
    for (int c = 0; c < F_HID; c++) {
        f[c] += __shfl_xor(f[c], 1, 64);
        f[c] += __shfl_xor(f[c], 2, 64);
    }
    if (node < N_NODES && q == 0) {
        float di = dinv[node];
#pragma unroll
        for (int c = 0; c < F_HID; c++)
            hbuf[nl][c] = fmaxf(di * f[c] + b2s[c], 0.0f);
    }
    __syncthreads();
    if (t < 8 * F_HID) {
        int l = t >> 4, ch = t & 15;
        int g = bl[0] + l;
        if (g < N_GRAPHS) {
            float s = 0.0f;
            int m = 0;
            for (int n0 = 0; n0 < PN; n0++) {
                int n = (n0 + (ch << 2)) & (PN - 1);
                if (bl[n] == g) { s += hbuf[n][ch]; m++; }
            }
            if (m > 0) atomicAdd(&out[g * F_HID + ch], s / cnt[g]);
        }
    }
}

// ---------------- launcher ----------------

extern "C" void kernel_launch(void* const* d_in, const int* in_sizes, int n_in,
                              void* d_out, int out_size, void* d_ws, size_t ws_size,
                              hipStream_t stream) {
    const float* x     = (const float*)d_in[0];
    const int*   ei    = (const int*)d_in[1];   // [2, N_EDGES]
    const int*   batch = (const int*)d_in[2];
    const float* W1    = (const float*)d_in[3];
    const float* b1    = (const float*)d_in[4];
    const float* W2    = (const float*)d_in[5];
    const float* b2    = (const float*)d_in[6];
    float* out = (float*)d_out;

    int*            H      = (int*)d_ws;                                   // NBLK*HPAD
    int*            Hc     = H + (size_t)NBLK * HPAD;                      // NBLK*HPAD
    int*            cnt_b  = Hc + (size_t)NBLK * HPAD;                     // 512
    unsigned short* rnk_e  = (unsigned short*)(cnt_b + 512);               // N_EDGES ushort
    unsigned*       packed = (unsigned*)(rnk_e + (size_t)N_EDGES);         // NBKT*CAP
    int2*           rowbc  = (int2*)(packed + (size_t)NBKT * CAP);         // N int2
    int*            col    = (int*)(rowbc + N_NODES);                      // NBKT*CAP
    float*          dinv   = (float*)(col + (size_t)NBKT * CAP);           // N
    unsigned short* pb_a   = (unsigned short*)(dinv + N_NODES);            // N*16 bf16
    unsigned short* pb_b   = pb_a + (size_t)N_NODES * F_HID;               // N*16 bf16
    float*          cnt    = (float*)(pb_b + (size_t)N_NODES * F_HID);     // 512

    const int* src = ei;
    const int* dst = ei + N_EDGES;

    // mutable copies for the args array
    const float* ax = x; const int* aei = ei; const int* abatch = batch;
    const float* aW1 = W1; const float* ab1 = b1; const float* aW2 = W2;
    const float* ab2 = b2; float* aout = out;
    int* aH = H; int* aHc = Hc; int* acnt_b = cnt_b;
    unsigned short* arnk_e = rnk_e; unsigned* apacked = packed;
    int2* arowbc = rowbc; int* acol = col; float* adinv = dinv;
    unsigned short* apb_a = pb_a; unsigned short* apb_b = pb_b; float* acnt = cnt;

    void* args[] = {&ax, &aei, &abatch, &aW1, &ab1, &aW2, &ab2, &aout,
                    &aH, &aHc, &acnt_b, &arnk_e, &apacked, &arowbc, &acol,
                    &adinv, &apb_a, &apb_b, &acnt};

    hipError_t err = hipLaunchCooperativeKernel((const void*)k_fused,
                                                dim3(GRID_F), dim3(512),
                                                args, 0, stream);
    if (err != hipSuccess) {
        // fallback: verified 7-kernel pipeline (r8)
        (void)hipGetLastError();                    // clear sticky error
        k_zero   <<<(N_GRAPHS * F_HID + 255) / 256, 256, 0, stream>>>(out, cnt);
        k_count  <<<NBLK, PBLK, 0, stream>>>(dst, batch, H, Hc, rnk_e, cnt);
        k_scan   <<<NBKT, 256, 0, stream>>>(H, cnt_b);
        k_scatter<<<NBLK, PBLK, 0, stream>>>(src, dst, H, Hc, rnk_e, packed);
        k_csr    <<<NBKT, 512, 0, stream>>>(cnt_b, packed, x, W1, rowbc, col, dinv, pb_a);
        k_pull1  <<<NPB, 256, 0, stream>>>(rowbc, col, pb_a, dinv, W2, b1, pb_b);
        k_pull2  <<<NPB, 256, 0, stream>>>(rowbc, col, pb_b, dinv, batch, b2, cnt, out);
    }
}

// Round 10
// 172.488 us; speedup vs baseline: 3.4261x; 3.4261x over previous
//
#include <hip/hip_runtime.h>

#define N_NODES  100000
#define N_EDGES  3200000
#define N_GRAPHS 512
#define F_IN     5
#define F_HID    16

#define PBLK   512                      // sort block size
#define CHUNK  4096                     // edges per sort block
#define NBLK   ((N_EDGES + CHUNK - 1) / CHUNK)          // 782
#define BKT_NODES 256                   // nodes per coarse bucket
#define NBKT ((N_NODES + BKT_NODES - 1) / BKT_NODES)    // 391
#define HPAD   512                      // H row stride (bucket index within block row)
#define CAP    10240                    // per-bucket segment capacity (mean 8184, +23 sigma)

// ---------------- helpers ----------------

__device__ inline unsigned short f2bf(float f) {
    unsigned u = __float_as_uint(f);
    return (unsigned short)((u + 0x7fffu + ((u >> 16) & 1u)) >> 16);   // RNE
}
__device__ inline float bf2f(unsigned short h) {
    return __uint_as_float(((unsigned)h) << 16);
}
__device__ inline float4 cvt4(ushort4 u) {
    return make_float4(bf2f(u.x), bf2f(u.y), bf2f(u.z), bf2f(u.w));
}
__device__ inline float4 shfl_xor4(float4 v, int m) {
    return make_float4(__shfl_xor(v.x, m, 64), __shfl_xor(v.y, m, 64),
                       __shfl_xor(v.z, m, 64), __shfl_xor(v.w, m, 64));
}

// block-wide inclusive scan via wave shfl; NW = number of waves (<=16)
template <int NW>
__device__ inline int block_incl_scan(int v, int t, int* wsum) {
    int lane = t & 63, wave = t >> 6;
    int x = v;
#pragma unroll
    for (int o = 1; o < 64; o <<= 1) {
        int y = __shfl_up(x, o, 64);
        if (lane >= o) x += y;
    }
    if (lane == 63) wsum[wave] = x;
    __syncthreads();
    if (t < 64) {
        int w = (t < NW) ? wsum[t] : 0;
#pragma unroll
        for (int o = 1; o < NW; o <<= 1) {
            int y = __shfl_up(w, o, 64);
            if (t >= o) w += y;
        }
        if (t < NW) wsum[t] = w;
    }
    __syncthreads();
    return x + (wave ? wsum[wave - 1] : 0);
}

// half-row gather (len % 8 == 0): half h takes 8-blocks h, h+2, h+4, ...
// channels 4j..4j+3. Dummy entries point at zeroed row N_NODES.
__device__ inline float4 row_gather8s(const ushort4* __restrict__ pb4, int i, int j,
                                      int half, int beg, int len,
                                      const int* __restrict__ col) {
    float4 acc = half ? make_float4(0.f, 0.f, 0.f, 0.f)
                      : cvt4(pb4[i * 4 + j]);          // self loop once
    for (int k = half * 8; k < len; k += 16) {
        int4 c0 = *(const int4*)(col + beg + k);
        int4 c1 = *(const int4*)(col + beg + k + 4);
        ushort4 a0 = pb4[c0.x * 4 + j], a1 = pb4[c0.y * 4 + j];
        ushort4 a2 = pb4[c0.z * 4 + j], a3 = pb4[c0.w * 4 + j];
        ushort4 a4 = pb4[c1.x * 4 + j], a5 = pb4[c1.y * 4 + j];
        ushort4 a6 = pb4[c1.z * 4 + j], a7 = pb4[c1.w * 4 + j];
        float4 f0 = cvt4(a0), f1 = cvt4(a1), f2 = cvt4(a2), f3 = cvt4(a3);
        float4 f4 = cvt4(a4), f5 = cvt4(a5), f6 = cvt4(a6), f7 = cvt4(a7);
        acc.x += ((f0.x + f1.x) + (f2.x + f3.x)) + ((f4.x + f5.x) + (f6.x + f7.x));
        acc.y += ((f0.y + f1.y) + (f2.y + f3.y)) + ((f4.y + f5.y) + (f6.y + f7.y));
        acc.z += ((f0.z + f1.z) + (f2.z + f3.z)) + ((f4.z + f5.z) + (f6.z + f7.z));
        acc.w += ((f0.w + f1.w) + (f2.w + f3.w)) + ((f4.w + f5.w) + (f6.w + f7.w));
    }
    return acc;
}

// ---------------- kernels ----------------

__global__ void k_zero(float* __restrict__ out, float* __restrict__ cnt,
                       unsigned short* __restrict__ pb_a,
                       unsigned short* __restrict__ pb_b) {
    int i = blockIdx.x * blockDim.x + threadIdx.x;
    if (i < N_GRAPHS * F_HID) out[i] = 0.0f;
    if (i < N_GRAPHS) cnt[i] = 0.0f;
    if (i < F_HID) {                       // zero the dummy rows
        pb_a[(size_t)N_NODES * F_HID + i] = 0;
        pb_b[(size_t)N_NODES * F_HID + i] = 0;
    }
}

// phase 1 of 3-phase counting sort: per-block histogram of dst>>8, written
// atomics-free to H[blk][bucket]. Blocks blk < NBKT also count nodes-per-graph
// from the sorted batch array (block b covers nodes [b*256, b*256+256)).
__global__ __launch_bounds__(PBLK) void k_count(const int* __restrict__ dst,
                                                const int* __restrict__ batch,
                                                int* __restrict__ H,
                                                float* __restrict__ cnt) {
    __shared__ int hist[HPAD];
    __shared__ int bcnt[8];
    __shared__ int g0s;
    int t = threadIdx.x, blk = blockIdx.x;
    int chunk0 = blk * CHUNK;
    int n4 = min(CHUNK, N_EDGES - chunk0) >> 2;
    hist[t] = 0;
    if (t < 8) bcnt[t] = 0;
    if (t == 0 && blk < NBKT) {
        int nb = blk * BKT_NODES;
        g0s = batch[nb < N_NODES ? nb : N_NODES - 1];
    }
    __syncthreads();
    const int4* d4 = (const int4*)(dst + chunk0);
#pragma unroll
    for (int i = 0; i < CHUNK / 4 / PBLK; i++) {
        int k = t + i * PBLK;
        if (k < n4) {
            int4 d = d4[k];
            atomicAdd(&hist[d.x >> 8], 1);
            atomicAdd(&hist[d.y >> 8], 1);
            atomicAdd(&hist[d.z >> 8], 1);
            atomicAdd(&hist[d.w >> 8], 1);
        }
    }
    if (blk < NBKT && t < BKT_NODES) {
        int i2 = blk * BKT_NODES + t;
        if (i2 < N_NODES) {
            int g = batch[i2];
            int l = g - g0s;
            if (l >= 0 && l < 8) atomicAdd(&bcnt[l], 1);
            else atomicAdd(&cnt[g], 1.0f);
        }
    }
    __syncthreads();
    H[blk * HPAD + t] = hist[t];                    // coalesced, no atomics
    if (blk < NBKT && t < 8 && bcnt[t] > 0) atomicAdd(&cnt[g0s + t], (float)bcnt[t]);
}

// phase 2: per bucket, exclusive scan of counts across blocks (in place),
// exact bucket total -> cnt_b. One block per bucket.
__global__ __launch_bounds__(256) void k_scan(int* __restrict__ H,
                                              int* __restrict__ cnt_b) {
    __shared__ int wsum[8];
    int b = blockIdx.x, t = threadIdx.x;
    int v[4];
    int s = 0;
#pragma unroll
    for (int i = 0; i < 4; i++) {
        int pos = t * 4 + i;
        v[i] = (pos < NBLK) ? H[pos * HPAD + b] : 0;
        s += v[i];
    }
    int incl = block_incl_scan<4>(s, t, wsum);
    int run = incl - s;
#pragma unroll
    for (int i = 0; i < 4; i++) {
        int pos = t * 4 + i;
        if (pos < NBLK) H[pos * HPAD + b] = run;
        run += v[i];
    }
    if (t == 255) cnt_b[b] = incl;                  // grand total for bucket b
}

// phase 3: re-read edges, block-local counting sort into LDS, then a
// coalesced flush to exact precomputed global positions. No global atomics.
__global__ __launch_bounds__(PBLK) void k_scatter(const int* __restrict__ src,
                                                  const int* __restrict__ dst,
                                                  const int* __restrict__ H,
                                                  unsigned* __restrict__ packed) {
    __shared__ int hist[HPAD];
    __shared__ int scn[HPAD];
    __shared__ int rnk[HPAD];
    __shared__ int base[HPAD];
    __shared__ int wsum[8];
    __shared__ unsigned pkd[CHUNK];                 // 16 KiB
    __shared__ unsigned short bkt[CHUNK];           // 8 KiB
    int t = threadIdx.x, blk = blockIdx.x;
    int chunk0 = blk * CHUNK;
    int n = min(CHUNK, N_EDGES - chunk0);
    int n4 = n >> 2;
    hist[t] = 0;
    base[t] = H[blk * HPAD + t];                    // coalesced scanned bases
    __syncthreads();
    const int4* s4 = (const int4*)(src + chunk0);
    const int4* d4 = (const int4*)(dst + chunk0);
    int4 lsv[CHUNK / 4 / PBLK], ldv[CHUNK / 4 / PBLK];
#pragma unroll
    for (int i = 0; i < CHUNK / 4 / PBLK; i++) {    // static idx -> registers
        int k = t + i * PBLK;
        if (k < n4) {
            lsv[i] = s4[k];
            ldv[i] = d4[k];
            atomicAdd(&hist[ldv[i].x >> 8], 1);
            atomicAdd(&hist[ldv[i].y >> 8], 1);
            atomicAdd(&hist[ldv[i].z >> 8], 1);
            atomicAdd(&hist[ldv[i].w >> 8], 1);
        }
    }
    __syncthreads();
    int v = hist[t];
    int incl = block_incl_scan<8>(v, t, wsum);
    int excl = incl - v;
    scn[t] = excl;
    rnk[t] = excl;
    __syncthreads();
#pragma unroll
    for (int i = 0; i < CHUNK / 4 / PBLK; i++) {
        int k = t + i * PBLK;
        if (k < n4) {
            int ds0 = ldv[i].x, ds1 = ldv[i].y, ds2 = ldv[i].z, ds3 = ldv[i].w;
            int ss0 = lsv[i].x, ss1 = lsv[i].y, ss2 = lsv[i].z, ss3 = lsv[i].w;
            int b0 = ds0 >> 8, b1 = ds1 >> 8, b2 = ds2 >> 8, b3 = ds3 >> 8;
            int r0 = atomicAdd(&rnk[b0], 1);
            pkd[r0] = ((unsigned)ss0 << 8) | (unsigned)(ds0 & 255);
            bkt[r0] = (unsigned short)b0;
            int r1 = atomicAdd(&rnk[b1], 1);
            pkd[r1] = ((unsigned)ss1 << 8) | (unsigned)(ds1 & 255);
            bkt[r1] = (unsigned short)b1;
            int r2 = atomicAdd(&rnk[b2], 1);
            pkd[r2] = ((unsigned)ss2 << 8) | (unsigned)(ds2 & 255);
            bkt[r2] = (unsigned short)b2;
            int r3 = atomicAdd(&rnk[b3], 1);
            pkd[r3] = ((unsigned)ss3 << 8) | (unsigned)(ds3 & 255);
            bkt[r3] = (unsigned short)b3;
        }
    }
    __syncthreads();
    for (int p = t; p < n; p += PBLK) {             // coalesced flush
        int b = bkt[p];
        packed[(size_t)b * CAP + base[b] + (p - scn[b])] = pkd[p];
    }
}

// per coarse bucket: node-level counting sort of the dense segment into
// BUCKET-LOCAL col (rows padded to multiple of 8 with dummy node N_NODES);
// emits per-node (beg,len), dinv, and fused layer-1 transform
// pb = bf16((x @ W1) * dinv). Packed entries staged in LDS during the hist
// pass so phase 2 never re-reads global.
// DELTA vs r2 (175 us verified): 1024 threads instead of 512 -- k_csr's
// occupancy is grid-limited (391 blocks, ~1.5/CU), so doubling block size
// doubles waves/CU (16->32 where 2 blocks land) for the latency-bound
// staging + rank-scatter loops. Same LDS (40 KiB), same algorithm.
__global__ __launch_bounds__(1024) void k_csr(const int* __restrict__ cnt_b,
                                              const unsigned* __restrict__ packed,
                                              const float* __restrict__ x,
                                              const float* __restrict__ W1,
                                              int2* __restrict__ rowbc,
                                              int* __restrict__ col,
                                              float* __restrict__ dinv,
                                              unsigned short* __restrict__ pb) {
    __shared__ int hist[BKT_NODES];
    __shared__ int rnk[BKT_NODES];
    __shared__ int wsum[16];
    __shared__ int tots;
    __shared__ float w1[F_IN * F_HID];
    __shared__ unsigned pkd[CAP];                      // 40 KiB staged entries
    int b = blockIdx.x, t = threadIdx.x;
    int base = b * CAP;
    if (t < BKT_NODES) hist[t] = 0;
    if (t == 0) tots = min(cnt_b[b], CAP);
    if (t >= 1024 - F_IN * F_HID) w1[t - (1024 - F_IN * F_HID)] = W1[t - (1024 - F_IN * F_HID)];
    __syncthreads();
    int tot = tots;
    const unsigned* pk = packed + (size_t)b * CAP;
    for (int k = t; k < tot; k += 1024) {
        unsigned u = pk[k];
        pkd[k] = u;
        atomicAdd(&hist[u & 255], 1);
    }
    __syncthreads();
    int v = (t < BKT_NODES) ? hist[t] : 0;
    int len = (v + 7) & ~7;                       // padded row length
    int incl = block_incl_scan<16>(len, t, wsum);
    int excl = incl - len;
    if (t < BKT_NODES) rnk[t] = excl;
    __syncthreads();
    for (int e = t; e < tot; e += 1024) {         // rank+scatter from LDS
        unsigned w = pkd[e];
        int r = atomicAdd(&rnk[w & 255], 1);
        if (r < CAP) col[base + r] = (int)(w >> 8);
    }
    if (t < BKT_NODES) {
        int node = b * BKT_NODES + t;
        if (node < N_NODES) {
            int mylen = min(len, ((CAP - min(excl, CAP)) & ~7));
            for (int q = v; q < mylen; q++) {     // pad with dummy node
                int r = excl + q;
                if (r < CAP) col[base + r] = N_NODES;
            }
            rowbc[node] = make_int2(base + excl, mylen);
            float di = rsqrtf((float)(1 + v));
            dinv[node] = di;
            float xi[F_IN];
#pragma unroll
            for (int k = 0; k < F_IN; k++) xi[k] = x[node * F_IN + k];
            float hv[F_HID];
#pragma unroll
            for (int c = 0; c < F_HID; c++) {
                float h = 0.0f;
#pragma unroll
                for (int k = 0; k < F_IN; k++) h += xi[k] * w1[k * F_HID + c];
                hv[c] = h * di;
            }
            unsigned pkk[8];
#pragma unroll
            for (int q = 0; q < 8; q++)
                pkk[q] = (unsigned)f2bf(hv[2 * q]) | ((unsigned)f2bf(hv[2 * q + 1]) << 16);
            uint4* d4 = (uint4*)(pb + (size_t)node * F_HID);
            d4[0] = make_uint4(pkk[0], pkk[1], pkk[2], pkk[3]);
            d4[1] = make_uint4(pkk[4], pkk[5], pkk[6], pkk[7]);
        }
    }
}

// fused pull + layer-1 epilogue + layer-2 transform; 8 threads/node
// (two halves of the row, combined via shfl_xor 4)
__global__ __launch_bounds__(256) void k_pull_mid(const int2* __restrict__ rowbc,
                                                  const int* __restrict__ col,
                                                  const unsigned short* __restrict__ pb,
                                                  const float* __restrict__ dinv,
                                                  const float* __restrict__ W2,
                                                  const float* __restrict__ b1,
                                                  unsigned short* __restrict__ pb2) {
    __shared__ float w[F_HID * F_HID];
    __shared__ float bb[F_HID];
    int t = threadIdx.x;
    w[t] = W2[t];                        // blockDim == 256 == F_HID*F_HID
    if (t < F_HID) bb[t] = b1[t];
    __syncthreads();
    int gid = blockIdx.x * 256 + t;      // grid = N_NODES*8/256 exactly
    int i = gid >> 3;
    int half = (gid >> 2) & 1;
    int j = gid & 3;
    int2 rc = rowbc[i];
    float4 acc = row_gather8s((const ushort4*)pb, i, j, half, rc.x, rc.y, col);
    acc.x += __shfl_xor(acc.x, 4, 64);
    acc.y += __shfl_xor(acc.y, 4, 64);
    acc.z += __shfl_xor(acc.z, 4, 64);
    acc.w += __shfl_xor(acc.w, 4, 64);
    float di = dinv[i];
    float4 mine;
    mine.x = fmaxf(di * acc.x + bb[4 * j + 0], 0.0f);
    mine.y = fmaxf(di * acc.y + bb[4 * j + 1], 0.0f);
    mine.z = fmaxf(di * acc.z + bb[4 * j + 2], 0.0f);
    mine.w = fmaxf(di * acc.w + bb[4 * j + 3], 0.0f);
    float4 o1 = shfl_xor4(mine, 1);
    float4 o2 = shfl_xor4(mine, 2);
    float4 o3 = shfl_xor4(mine, 3);
    float4 hq0 = (j == 0) ? mine : ((j == 1) ? o1 : ((j == 2) ? o2 : o3));
    float4 hq1 = (j == 1) ? mine : ((j == 0) ? o1 : ((j == 3) ? o2 : o3));
    float4 hq2 = (j == 2) ? mine : ((j == 3) ? o1 : ((j == 0) ? o2 : o3));
    float4 hq3 = (j == 3) ? mine : ((j == 2) ? o1 : ((j == 1) ? o2 : o3));
    float hc[F_HID] = {hq0.x, hq0.y, hq0.z, hq0.w, hq1.x, hq1.y, hq1.z, hq1.w,
                       hq2.x, hq2.y, hq2.z, hq2.w, hq3.x, hq3.y, hq3.z, hq3.w};
    float m0 = 0.0f, m1 = 0.0f, m2 = 0.0f, m3 = 0.0f;
#pragma unroll
    for (int c = 0; c < F_HID; c++) {
        float4 wv = *(const float4*)&w[c * F_HID + 4 * j];
        float hv = hc[c];
        m0 += hv * wv.x; m1 += hv * wv.y; m2 += hv * wv.z; m3 += hv * wv.w;
    }
    if (half == 0) {
        unsigned p0 = (unsigned)f2bf(m0 * di) | ((unsigned)f2bf(m1 * di) << 16);
        unsigned p1 = (unsigned)f2bf(m2 * di) | ((unsigned)f2bf(m3 * di) << 16);
        *(uint2*)(pb2 + (size_t)i * F_HID + 4 * j) = make_uint2(p0, p1);
    }
}

// fused pull + layer-2 epilogue + mean-pool (division folded in via cnt
// computed by k_count); 8 threads/node
__global__ __launch_bounds__(256) void k_pull_pool(const int2* __restrict__ rowbc,
                                                   const int* __restrict__ col,
                                                   const unsigned short* __restrict__ pb,
                                                   const float* __restrict__ dinv,
                                                   const int* __restrict__ batch,
                                                   const float* __restrict__ b2,
                                                   const float* __restrict__ cnt,
                                                   float* __restrict__ out) {
    __shared__ float bb[F_HID];
    __shared__ float acc2[8][F_HID];
    __shared__ int gcnt[8];
    __shared__ int g0s;
    int t = threadIdx.x;
    if (t < F_HID) bb[t] = b2[t];
    if (t < 8) gcnt[t] = 0;
    if (t < 8 * F_HID) ((float*)acc2)[t] = 0.0f;
    int blk0node = blockIdx.x * 32;                 // 32 nodes per block
    if (t == 0) g0s = batch[blk0node < N_NODES ? blk0node : N_NODES - 1];
    __syncthreads();
    int g0 = g0s;
    int gid = blockIdx.x * 256 + t;
    int i = gid >> 3;
    int half = (gid >> 2) & 1;
    int j = gid & 3;
    int2 rc = rowbc[i];
    float4 acc = row_gather8s((const ushort4*)pb, i, j, half, rc.x, rc.y, col);
    acc.x += __shfl_xor(acc.x, 4, 64);
    acc.y += __shfl_xor(acc.y, 4, 64);
    acc.z += __shfl_xor(acc.z, 4, 64);
    acc.w += __shfl_xor(acc.w, 4, 64);
    if (half == 0) {
        float di = dinv[i];
        float h0 = fmaxf(di * acc.x + bb[4 * j + 0], 0.0f);
        float h1 = fmaxf(di * acc.y + bb[4 * j + 1], 0.0f);
        float h2 = fmaxf(di * acc.z + bb[4 * j + 2], 0.0f);
        float h3 = fmaxf(di * acc.w + bb[4 * j + 3], 0.0f);
        int g = batch[i];
        int l = g - g0;
        if (l >= 0 && l < 8) {
            atomicAdd(&acc2[l][4 * j + 0], h0);
            atomicAdd(&acc2[l][4 * j + 1], h1);
            atomicAdd(&acc2[l][4 * j + 2], h2);
            atomicAdd(&acc2[l][4 * j + 3], h3);
            if (j == 0) atomicAdd(&gcnt[l], 1);
        } else {
            float inv = 1.0f / cnt[g];
            atomicAdd(&out[g * F_HID + 4 * j + 0], h0 * inv);
            atomicAdd(&out[g * F_HID + 4 * j + 1], h1 * inv);
            atomicAdd(&out[g * F_HID + 4 * j + 2], h2 * inv);
            atomicAdd(&out[g * F_HID + 4 * j + 3], h3 * inv);
        }
    }
    __syncthreads();
    if (t < 8 * F_HID) {
        int l = t >> 4, c = t & 15;
        if (gcnt[l] > 0) {
            float inv = 1.0f / cnt[g0 + l];
            atomicAdd(&out[(g0 + l) * F_HID + c], acc2[l][c] * inv);
        }
    }
}

// ---------------- launcher ----------------

extern "C" void kernel_launch(void* const* d_in, const int* in_sizes, int n_in,
                              void* d_out, int out_size, void* d_ws, size_t ws_size,
                              hipStream_t stream) {
    const float* x     = (const float*)d_in[0];
    const int*   ei    = (const int*)d_in[1];   // [2, N_EDGES]
    const int*   batch = (const int*)d_in[2];
    const float* W1    = (const float*)d_in[3];
    const float* b1    = (const float*)d_in[4];
    const float* W2    = (const float*)d_in[5];
    const float* b2    = (const float*)d_in[6];
    float* out = (float*)d_out;

    int*            H      = (int*)d_ws;                                   // NBLK*HPAD
    int*            cnt_b  = H + (size_t)NBLK * HPAD;                      // 512
    unsigned*       packed = (unsigned*)(cnt_b + 512);                     // NBKT*CAP
    int2*           rowbc  = (int2*)(packed + (size_t)NBKT * CAP);         // N int2
    int*            col    = (int*)(rowbc + N_NODES);                      // NBKT*CAP
    float*          dinv   = (float*)(col + (size_t)NBKT * CAP);           // N
    unsigned short* pb_a   = (unsigned short*)(dinv + N_NODES);            // (N+1)*16
    unsigned short* pb_b   = pb_a + (size_t)(N_NODES + 1) * F_HID;         // (N+1)*16
    float*          cnt    = (float*)(pb_b + (size_t)(N_NODES + 1) * F_HID); // 512

    const int* src = ei;
    const int* dst = ei + N_EDGES;

    const int nb_pull = (N_NODES * 8) / 256;        // 3125 exactly

    k_zero<<<(N_GRAPHS * F_HID + 255) / 256, 256, 0, stream>>>(out, cnt, pb_a, pb_b);
    k_count<<<NBLK, PBLK, 0, stream>>>(dst, batch, H, cnt);
    k_scan<<<NBKT, 256, 0, stream>>>(H, cnt_b);
    k_scatter<<<NBLK, PBLK, 0, stream>>>(src, dst, H, packed);
    k_csr<<<NBKT, 1024, 0, stream>>>(cnt_b, packed, x, W1, rowbc, col, dinv, pb_a);
    k_pull_mid<<<nb_pull, 256, 0, stream>>>(rowbc, col, pb_a, dinv, W2, b1, pb_b);
    k_pull_pool<<<nb_pull, 256, 0, stream>>>(rowbc, col, pb_b, dinv, batch, b2,
                                             cnt, out);
}